// Round 1
// baseline (202.474 us; speedup 1.0000x reference)
//
#include <hip/hip_runtime.h>
#include <hip/hip_fp16.h>
#include <math.h>

#define N_NODES 50000
#define N_REL   1000
#define D       128
#define NNZ     800000

#define NTHR 512
#define NB1  256                   // blocks for k1/place
#define TS   2048                  // scan tile size (4 elems/thread)
#define NT   25                    // ceil(50000/2048)
#define CNTP (NT * TS)             // 51200 padded count array

// ======== K1: fused relation scores + f32->f16 convert + row-count histogram ========
__global__ void __launch_bounds__(NTHR)
k1_kernel(const int* __restrict__ rows, const float* __restrict__ dual,
          const float* __restrict__ conv_w, const float* __restrict__ conv_b,
          const float* __restrict__ inlayer, float* __restrict__ exp_scores,
          unsigned* __restrict__ cnt, __half2* __restrict__ hinl) {
    int t = threadIdx.x;
    int gtid = blockIdx.x * NTHR + t;
    int lane = t & 63;

    // scores: one wave per relation (waves 0..999 across blocks 0..124)
    int wid = gtid >> 6;
    if (wid < N_REL) {
        const float* row = dual + (long)wid * D;
        float s = row[lane] * conv_w[lane] + row[lane + 64] * conv_w[lane + 64];
        #pragma unroll
        for (int off = 32; off > 0; off >>= 1) s += __shfl_down(s, off);
        if (lane == 0) {
            float v = s + conv_b[0];
            v = (v >= 0.f) ? v : 0.01f * v;            // leaky_relu
            exp_scores[wid] = expf(v);                 // scores ~N(0,1): safe
        }
    }

    // f32 -> f16 convert (grid-stride, coalesced)
    const float2* src = (const float2*)inlayer;
    for (int i = gtid; i < N_NODES * D / 2; i += NB1 * NTHR)
        hinl[i] = __float22half2_rn(src[i]);

    // row-count histogram: 800K scattered 4B atomics over 200KB (L2-resident)
    const int4* r4 = (const int4*)rows;
    for (int j = gtid; j < NNZ / 4; j += NB1 * NTHR) {
        int4 rr = r4[j];
        atomicAdd(&cnt[rr.x], 1u);
        atomicAdd(&cnt[rr.y], 1u);
        atomicAdd(&cnt[rr.z], 1u);
        atomicAdd(&cnt[rr.w], 1u);
    }
}

// ======== K2: in-place exclusive scan of cnt[50000] (decoupled lookback, 25 tiles) ====
__global__ void __launch_bounds__(NTHR)
scan_kernel(unsigned* __restrict__ cnt, unsigned long long* __restrict__ state,
            unsigned* __restrict__ ticket) {
    __shared__ unsigned wsum[8];
    __shared__ unsigned sh_agg, sh_base;
    __shared__ int sh_tile;
    int t = threadIdx.x, lane = t & 63, w = t >> 6;

    if (t == 0) sh_tile = (int)atomicAdd(ticket, 1u);
    __syncthreads();
    int tile = sh_tile;

    int base = tile * TS + t * 4;          // always < CNTP (padded, zeroed)
    uint4 x = *(uint4*)&cnt[base];
    unsigned run = x.x + x.y + x.z + x.w;

    unsigned v = run;                      // wave-inclusive scan of thread sums
    #pragma unroll
    for (int off = 1; off < 64; off <<= 1) {
        unsigned y = __shfl_up(v, off);
        if (lane >= off) v += y;
    }
    if (lane == 63) wsum[w] = v;
    __syncthreads();
    if (t == 0) {
        unsigned acc = 0;
        #pragma unroll
        for (int k = 0; k < 8; ++k) { unsigned tmp = wsum[k]; wsum[k] = acc; acc += tmp; }
        sh_agg = acc;
    }
    __syncthreads();
    unsigned tbase = wsum[w] + (v - run);  // exclusive base for this thread

    if (t == 0)
        atomicExch(&state[tile], (1ULL << 32) | (unsigned long long)sh_agg);
    if (t < 64) {
        unsigned sum = 0;
        if (tile > 0) {
            int base_pred = tile - 1;
            for (;;) {
                int pred = base_pred - t;
                unsigned long long sv;
                if (pred >= 0) {
                    do { sv = atomicAdd(&state[pred], 0ULL); } while ((sv >> 32) == 0ULL);
                } else {
                    sv = (2ULL << 32);
                }
                unsigned long long m2 = __ballot((sv >> 32) == 2ULL);
                int l2 = (m2 != 0ULL) ? (__ffsll((long long)m2) - 1) : 64;
                unsigned contrib = ((int)t <= l2) ? (unsigned)sv : 0u;
                #pragma unroll
                for (int off = 32; off > 0; off >>= 1)
                    contrib += __shfl_down(contrib, off);
                sum += __shfl(contrib, 0);
                if (m2 != 0ULL) break;
                base_pred -= 64;
            }
        }
        if (t == 0) {
            sh_base = sum;
            atomicExch(&state[tile],
                       (2ULL << 32) | (unsigned long long)(sum + sh_agg));
        }
    }
    __syncthreads();
    unsigned g = sh_base + tbase;
    uint4 o;
    o.x = g; o.y = g + x.x; o.z = g + x.x + x.y; o.w = g + x.x + x.y + x.z;
    *(uint4*)&cnt[base] = o;
}

// ======== K3: place edges via atomic cursors on starts[]; fused denom reduction ======
__global__ void __launch_bounds__(NTHR)
place_kernel(const int* __restrict__ rows, const int* __restrict__ cols,
             const int* __restrict__ rel, const float* __restrict__ exp_scores,
             unsigned* __restrict__ starts, int2* __restrict__ bpack,
             float* __restrict__ denom) {
    __shared__ float fpart[8];
    int t = threadIdx.x;
    int gtid = blockIdx.x * NTHR + t;
    int lane = t & 63, w = t >> 6;
    float dsum = 0.f;
    const int4* r4 = (const int4*)rows;
    const int4* c4 = (const int4*)cols;
    const int4* q4 = (const int4*)rel;
    for (int j = gtid; j < NNZ / 4; j += NB1 * NTHR) {
        int4 rr = r4[j]; int4 cc = c4[j]; int4 qq = q4[j];
        #pragma unroll
        for (int k = 0; k < 4; ++k) {
            int r = (k == 0) ? rr.x : (k == 1) ? rr.y : (k == 2) ? rr.z : rr.w;
            int c = (k == 0) ? cc.x : (k == 1) ? cc.y : (k == 2) ? cc.z : cc.w;
            int q = (k == 0) ? qq.x : (k == 1) ? qq.y : (k == 2) ? qq.z : qq.w;
            float wv = exp_scores[q];                  // 4KB table: L1-resident
            dsum += wv;
            unsigned pos = atomicAdd(&starts[r], 1u);  // exclusive -> inclusive
            int2 pk; pk.x = c; pk.y = __float_as_int(wv);  // unnormalized weight
            bpack[pos] = pk;
        }
    }
    #pragma unroll
    for (int off = 32; off > 0; off >>= 1) dsum += __shfl_down(dsum, off);
    if (lane == 0) fpart[w] = dsum;
    __syncthreads();
    if (t == 0) {
        float s = 0.f;
        #pragma unroll
        for (int k = 0; k < 8; ++k) s += fpart[k];
        atomicAdd(denom, s);
    }
}

// ======== K4: gather — fp16 rows, 16 lanes/row, 4 rows per load; /denom epilogue =====
__global__ void gather_kernel(const unsigned* __restrict__ starts,
                              const int2* __restrict__ bpack,
                              const __half2* __restrict__ hinl,
                              const float* __restrict__ denom,
                              float* __restrict__ out) {
    int node = blockIdx.x * (blockDim.x >> 6) + (threadIdx.x >> 6);
    int lane = threadIdx.x & 63;
    if (node >= N_NODES) return;
    // after place_kernel, starts[] is the INCLUSIVE prefix: seg = [starts[n-1], starts[n])
    int e = (int)starts[node];
    int s = (node > 0) ? (int)starts[node - 1] : 0;
    int quad = lane >> 4;                  // which of 4 rows per load
    int l16  = lane & 15;                  // 8-dim group within row
    float a0=0.f,a1=0.f,a2=0.f,a3=0.f,a4=0.f,a5=0.f,a6=0.f,a7=0.f;
    for (int base = s; base < e; base += 64) {
        int rem = e - base; if (rem > 64) rem = 64;
        int px = 0, py = 0;
        if (lane < rem) {
            int2 p = bpack[base + lane];   // coalesced 512B / 64 edges
            px = p.x; py = p.y;
        }
        for (int j = 0; j < rem; j += 16) {
            #pragma unroll
            for (int k = 0; k < 16; k += 4) {
                if (j + k < rem) {         // wave-uniform guard
                    int idx = j + k + quad;
                    int   c = __shfl(px, idx);           // 0 beyond rem -> w=0
                    float w = __int_as_float(__shfl(py, idx));
                    const __half2* hp = hinl + (long)c * (D / 2) + l16 * 4;
                    uint4 hv = *(const uint4*)hp;        // 8 halves (16B)
                    float2 f0 = __half22float2(*(const __half2*)&hv.x);
                    float2 f1 = __half22float2(*(const __half2*)&hv.y);
                    float2 f2 = __half22float2(*(const __half2*)&hv.z);
                    float2 f3 = __half22float2(*(const __half2*)&hv.w);
                    a0 += w * f0.x; a1 += w * f0.y;
                    a2 += w * f1.x; a3 += w * f1.y;
                    a4 += w * f2.x; a5 += w * f2.y;
                    a6 += w * f3.x; a7 += w * f3.y;
                }
            }
        }
    }
    // combine the 4 quads: butterfly over lane bits 4 and 5
    #define COMB(x) x += __shfl(x, lane ^ 16); x += __shfl(x, lane ^ 32);
    COMB(a0) COMB(a1) COMB(a2) COMB(a3) COMB(a4) COMB(a5) COMB(a6) COMB(a7)
    #undef COMB
    if (lane < 32) {                       // 32 lanes cover the 512B row store
        float inv = 1.0f / *denom;         // normalization deferred to epilogue
        float4 v;
        int hi = (lane >> 4) & 1;          // 0: dims 0-3 of group, 1: dims 4-7
        if (hi) { v.x = a4*inv; v.y = a5*inv; v.z = a6*inv; v.w = a7*inv; }
        else    { v.x = a0*inv; v.y = a1*inv; v.z = a2*inv; v.w = a3*inv; }
        *(float4*)(out + (long)node * D + l16 * 8 + hi * 4) = v;
    }
}

extern "C" void kernel_launch(void* const* d_in, const int* in_sizes, int n_in,
                              void* d_out, int out_size, void* d_ws, size_t ws_size,
                              hipStream_t stream) {
    const float* inlayer  = (const float*)d_in[0];
    const float* dual     = (const float*)d_in[1];
    const float* conv_w   = (const float*)d_in[2];
    const float* conv_b   = (const float*)d_in[3];
    const int*   edge_idx = (const int*)d_in[4];   // [2, NNZ]: rows then cols
    const int*   edge_rel = (const int*)d_in[5];
    float* out = (float*)d_out;
    const int* rows = edge_idx;
    const int* cols = edge_idx + NNZ;

    // workspace layout (16B aligned) — total ~19.5 MB
    char* ws = (char*)d_ws;
    float*              exp_scores = (float*)             (ws);             // 4 KB
    float*              denom      = (float*)             (ws + 4096);
    unsigned*           ticket     = (unsigned*)          (ws + 4160);
    unsigned long long* state      = (unsigned long long*)(ws + 4224);      // 25*8 B
    unsigned*           cnt        = (unsigned*)          (ws + 8192);      // 204.8 KB (padded to 51200)
    int2*               bpack      = (int2*)              (ws + 8192 + CNTP * 4);           // 6.4 MB
    __half2*            hinl       = (__half2*)           (ws + 8192 + CNTP * 4 + 8 * NNZ); // 12.8 MB

    // zero denom + ticket + state + cnt (incl. padding) in one 209 KB fill
    hipMemsetAsync(ws + 4096, 0, 4096 + CNTP * 4, stream);

    k1_kernel<<<NB1, NTHR, 0, stream>>>(rows, dual, conv_w, conv_b, inlayer,
                                        exp_scores, cnt, hinl);
    scan_kernel<<<NT, NTHR, 0, stream>>>(cnt, state, ticket);
    place_kernel<<<NB1, NTHR, 0, stream>>>(rows, cols, edge_rel, exp_scores,
                                           cnt, bpack, denom);
    int grid = (N_NODES + 3) / 4;   // 4 waves/block, one node per wave
    gather_kernel<<<grid, 256, 0, stream>>>(cnt, bpack, hinl, denom, out);
}